// Round 1
// baseline (5376.758 us; speedup 1.0000x reference)
//
#include <hip/hip_runtime.h>
#include <cstdint>
#include <cstddef>

#define EMBED  256
#define HIDDEN 512
#define VOCAB  32000
#define BATCH  16
#define TCAP   63
#define STEPS  1024   // BATCH * (TCAP + 1)

// ---------------------------------------------------------------------------
// helpers
// ---------------------------------------------------------------------------
__device__ __forceinline__ float sigmoid_f(float x) {
    return 1.0f / (1.0f + __expf(-x));
}
__device__ __forceinline__ float tanh_f(float x) {
    // overflow-safe tanh via exp of negative argument only
    float a = fabsf(x);
    float e = __expf(-2.0f * a);
    float r = (1.0f - e) / (1.0f + e);
    return copysignf(r, x);
}
// branchless 4-way select with static register indices (avoid scratch, rule #20)
__device__ __forceinline__ float sel4(float a0, float a1, float a2, float a3, int j) {
    float lo = (j & 1) ? a1 : a0;
    float hi = (j & 1) ? a3 : a2;
    return (j & 2) ? hi : lo;
}

// ---------------------------------------------------------------------------
// Kernel 1: persistent sequential LSTM scan.
// 32 WGs x 256 threads = 128 independent waves. Wave w owns h-elements
// j in [4w, 4w+4) i.e. 16 gate rows (4 gates x 4 elems). Weights live in
// VGPRs (W_hh 16x8/lane, W_ih 16x4/lane). h is exchanged via seq-tagged
// u64 relaxed agent-scope atomics in hbuf[2][HIDDEN]:  (tag s)<<32 | h[j].
// Buffer parity: version s lives in hbuf[s&1]. hbuf must be zeroed before
// launch (tag 0 == initial h == 0, so step 0 needs no special case).
// ---------------------------------------------------------------------------
__global__ __launch_bounds__(256, 1) void lstm_scan_kernel(
    const float* __restrict__ features,
    const int*   __restrict__ captions,
    const float* __restrict__ emb,
    const float* __restrict__ W_ih,
    const float* __restrict__ W_hh,
    const float* __restrict__ b_ih,
    const float* __restrict__ b_hh,
    unsigned long long* __restrict__ hbuf,   // [2][HIDDEN]
    float* __restrict__ hs)                  // [STEPS][HIDDEN]
{
    const int tid = threadIdx.x;
    const int rg  = tid >> 6;              // wave within WG
    const int kc  = tid & 63;              // lane
    const int w   = blockIdx.x * 4 + rg;   // global wave 0..127
    const int j0  = w * 4;                 // first owned h element

    // ---- load weight slices into registers (static-indexed arrays) ----
    float Whh[4][4][8];   // [gate][elem][k-chunk of 8]  k = kc*8 + kk
    float Wih[4][4][4];   // [gate][elem][k-chunk of 4]  k = kc*4 + kk
    float bias[4][4];
#pragma unroll
    for (int t = 0; t < 4; ++t) {
#pragma unroll
        for (int jj = 0; jj < 4; ++jj) {
            const int row = t * HIDDEN + j0 + jj;
            const float4* ph = (const float4*)(W_hh + (size_t)row * HIDDEN + kc * 8);
            float4 h0 = ph[0], h1 = ph[1];
            Whh[t][jj][0] = h0.x; Whh[t][jj][1] = h0.y; Whh[t][jj][2] = h0.z; Whh[t][jj][3] = h0.w;
            Whh[t][jj][4] = h1.x; Whh[t][jj][5] = h1.y; Whh[t][jj][6] = h1.z; Whh[t][jj][7] = h1.w;
            const float4* pi = (const float4*)(W_ih + (size_t)row * EMBED + kc * 4);
            float4 i0 = pi[0];
            Wih[t][jj][0] = i0.x; Wih[t][jj][1] = i0.y; Wih[t][jj][2] = i0.z; Wih[t][jj][3] = i0.w;
            bias[t][jj] = b_ih[row] + b_hh[row];
        }
    }

    // each lane tracks the cell state of element (kc & 3); 16-fold replicated,
    // deterministic because all inputs are wave-uniform after the butterfly.
    const int jsel = kc & 3;
    float c_state = 0.0f;

    // x for s = 0 is features row 0
    float xr[4];
    {
        const float4 v = *(const float4*)(features + kc * 4);
        xr[0] = v.x; xr[1] = v.y; xr[2] = v.z; xr[3] = v.w;
    }

    for (int s = 0; s < STEPS; ++s) {
        // ---- prefetch next x (no dependence on h) ----
        float xn[4] = {0.f, 0.f, 0.f, 0.f};
        if (s + 1 < STEPS) {
            const int sb = (s + 1) >> 6, st = (s + 1) & 63;
            const float* xp = (st == 0)
                ? (features + (size_t)sb * EMBED)
                : (emb + (size_t)captions[sb * TCAP + st - 1] * EMBED);
            const float4 v = *(const float4*)(xp + kc * 4);
            xn[0] = v.x; xn[1] = v.y; xn[2] = v.z; xn[3] = v.w;
        }

        // ---- issue first h poll round (latency overlaps x-FMAs below) ----
        const unsigned long long* hb = hbuf + (size_t)(s & 1) * HIDDEN + kc * 8;
        unsigned long long hv[8];
#pragma unroll
        for (int kk = 0; kk < 8; ++kk)
            hv[kk] = __hip_atomic_load(hb + kk, __ATOMIC_RELAXED, __HIP_MEMORY_SCOPE_AGENT);

        // ---- x contribution ----
        float acc[16];
#pragma unroll
        for (int t = 0; t < 4; ++t) {
#pragma unroll
            for (int jj = 0; jj < 4; ++jj) {
                float a = Wih[t][jj][0] * xr[0];
                a = fmaf(Wih[t][jj][1], xr[1], a);
                a = fmaf(Wih[t][jj][2], xr[2], a);
                a = fmaf(Wih[t][jj][3], xr[3], a);
                acc[t * 4 + jj] = a;
            }
        }

        // ---- finish poll: every lane needs its 8 h values tagged s ----
        const unsigned expect = (unsigned)s;
        for (;;) {
            bool ok = true;
#pragma unroll
            for (int kk = 0; kk < 8; ++kk)
                ok &= ((unsigned)(hv[kk] >> 32) == expect);
            if (ok) break;
#pragma unroll
            for (int kk = 0; kk < 8; ++kk)
                hv[kk] = __hip_atomic_load(hb + kk, __ATOMIC_RELAXED, __HIP_MEMORY_SCOPE_AGENT);
        }
        float hreg[8];
#pragma unroll
        for (int kk = 0; kk < 8; ++kk)
            hreg[kk] = __uint_as_float((unsigned)(hv[kk] & 0xffffffffULL));

        // ---- h contribution ----
#pragma unroll
        for (int t = 0; t < 4; ++t) {
#pragma unroll
            for (int jj = 0; jj < 4; ++jj) {
                float a = acc[t * 4 + jj];
#pragma unroll
                for (int kk = 0; kk < 8; ++kk)
                    a = fmaf(Whh[t][jj][kk], hreg[kk], a);
                acc[t * 4 + jj] = a;
            }
        }

        // ---- butterfly reduce all 16 partial sums across 64 lanes ----
#pragma unroll
        for (int e = 0; e < 16; ++e) {
            float a = acc[e];
            a += __shfl_xor(a, 1, 64);
            a += __shfl_xor(a, 2, 64);
            a += __shfl_xor(a, 4, 64);
            a += __shfl_xor(a, 8, 64);
            a += __shfl_xor(a, 16, 64);
            a += __shfl_xor(a, 32, 64);
            acc[e] = a;
        }

        // ---- cell update for element jsel (transcendentals parallel over lanes) ----
        float gi = sel4(acc[0],  acc[1],  acc[2],  acc[3],  jsel) + sel4(bias[0][0], bias[0][1], bias[0][2], bias[0][3], jsel);
        float gf = sel4(acc[4],  acc[5],  acc[6],  acc[7],  jsel) + sel4(bias[1][0], bias[1][1], bias[1][2], bias[1][3], jsel);
        float gg = sel4(acc[8],  acc[9],  acc[10], acc[11], jsel) + sel4(bias[2][0], bias[2][1], bias[2][2], bias[2][3], jsel);
        float go = sel4(acc[12], acc[13], acc[14], acc[15], jsel) + sel4(bias[3][0], bias[3][1], bias[3][2], bias[3][3], jsel);

        gi = sigmoid_f(gi);
        gf = sigmoid_f(gf);
        gg = tanh_f(gg);
        go = sigmoid_f(go);
        c_state = gf * c_state + gi * gg;
        const float hnew = go * tanh_f(c_state);

        // ---- publish: lanes 0..3 own distinct elements ----
        if (kc < 4) {
            const int j = j0 + kc;
            hs[(size_t)s * HIDDEN + j] = hnew;
            const unsigned long long pack =
                ((unsigned long long)(unsigned)(s + 1) << 32) |
                (unsigned long long)__float_as_uint(hnew);
            __hip_atomic_store(hbuf + (size_t)((s + 1) & 1) * HIDDEN + j, pack,
                               __ATOMIC_RELAXED, __HIP_MEMORY_SCOPE_AGENT);
        }

        xr[0] = xn[0]; xr[1] = xn[1]; xr[2] = xn[2]; xr[3] = xn[3];
    }
}

// ---------------------------------------------------------------------------
// Kernel 2: logits = hs @ W_out^T + b_out  (M=1024, N=32000, K=512), fp32.
// 64x64 tiles, K staged in 64-chunks, 4x4 micro-tile per thread.
// LDS rows padded to 65 floats: broadcast A-reads, 2-way (free) B-reads.
// ---------------------------------------------------------------------------
__global__ __launch_bounds__(256) void logits_kernel(
    const float* __restrict__ hs,
    const float* __restrict__ W_out,
    const float* __restrict__ b_out,
    float* __restrict__ out)
{
    __shared__ float As[64][65];
    __shared__ float Bs[64][65];
    const int tid = threadIdx.x;
    const int tx = tid & 15, ty = tid >> 4;
    const int v0 = blockIdx.x * 64;
    const int s0 = blockIdx.y * 64;
    float accv[4][4] = {};

    for (int k0 = 0; k0 < HIDDEN; k0 += 64) {
#pragma unroll
        for (int i = 0; i < 4; ++i) {
            const int idx = tid + i * 256;       // 0..1023
            const int r = idx >> 4, q = idx & 15;
            const float4 a = *(const float4*)(hs + (size_t)(s0 + r) * HIDDEN + k0 + q * 4);
            As[r][q * 4 + 0] = a.x; As[r][q * 4 + 1] = a.y;
            As[r][q * 4 + 2] = a.z; As[r][q * 4 + 3] = a.w;
            const float4 b = *(const float4*)(W_out + (size_t)(v0 + r) * HIDDEN + k0 + q * 4);
            Bs[r][q * 4 + 0] = b.x; Bs[r][q * 4 + 1] = b.y;
            Bs[r][q * 4 + 2] = b.z; Bs[r][q * 4 + 3] = b.w;
        }
        __syncthreads();
#pragma unroll 16
        for (int kk = 0; kk < 64; ++kk) {
            float av[4], bv[4];
#pragma unroll
            for (int i = 0; i < 4; ++i) av[i] = As[ty * 4 + i][kk];
#pragma unroll
            for (int j = 0; j < 4; ++j) bv[j] = Bs[tx * 4 + j][kk];
#pragma unroll
            for (int i = 0; i < 4; ++i)
#pragma unroll
                for (int j = 0; j < 4; ++j)
                    accv[i][j] = fmaf(av[i], bv[j], accv[i][j]);
        }
        __syncthreads();
    }

#pragma unroll
    for (int i = 0; i < 4; ++i) {
        const int s = s0 + ty * 4 + i;
#pragma unroll
        for (int j = 0; j < 4; ++j) {
            const int v = v0 + tx * 4 + j;
            out[(size_t)s * VOCAB + v] = accv[i][j] + b_out[v];
        }
    }
}

// ---------------------------------------------------------------------------
// Kernel 3: in-place row softmax over d_out, one WG per row of 32000.
// ---------------------------------------------------------------------------
__global__ __launch_bounds__(256) void softmax_kernel(float* __restrict__ out)
{
    const int row = blockIdx.x;
    float* p = out + (size_t)row * VOCAB;
    const int tid = threadIdx.x;
    __shared__ float redm[4];
    __shared__ float reds[4];

    float m = -3.402823466e38f;
    for (int idx = tid * 4; idx < VOCAB; idx += 1024) {
        const float4 v = *(const float4*)(p + idx);
        m = fmaxf(m, fmaxf(fmaxf(v.x, v.y), fmaxf(v.z, v.w)));
    }
#pragma unroll
    for (int d = 1; d < 64; d <<= 1) m = fmaxf(m, __shfl_xor(m, d, 64));
    if ((tid & 63) == 0) redm[tid >> 6] = m;
    __syncthreads();
    m = fmaxf(fmaxf(redm[0], redm[1]), fmaxf(redm[2], redm[3]));

    float sum = 0.f;
    for (int idx = tid * 4; idx < VOCAB; idx += 1024) {
        const float4 v = *(const float4*)(p + idx);
        sum += __expf(v.x - m) + __expf(v.y - m) + __expf(v.z - m) + __expf(v.w - m);
    }
#pragma unroll
    for (int d = 1; d < 64; d <<= 1) sum += __shfl_xor(sum, d, 64);
    if ((tid & 63) == 0) reds[tid >> 6] = sum;
    __syncthreads();
    sum = reds[0] + reds[1] + reds[2] + reds[3];
    const float inv = 1.0f / sum;

    for (int idx = tid * 4; idx < VOCAB; idx += 1024) {
        const float4 v = *(const float4*)(p + idx);
        float4 o;
        o.x = __expf(v.x - m) * inv;
        o.y = __expf(v.y - m) * inv;
        o.z = __expf(v.z - m) * inv;
        o.w = __expf(v.w - m) * inv;
        *(float4*)(p + idx) = o;
    }
}

// ---------------------------------------------------------------------------
// launch
// ---------------------------------------------------------------------------
extern "C" void kernel_launch(void* const* d_in, const int* in_sizes, int n_in,
                              void* d_out, int out_size, void* d_ws, size_t ws_size,
                              hipStream_t stream)
{
    const float* features = (const float*)d_in[0];
    const int*   captions = (const int*)d_in[1];
    const float* emb      = (const float*)d_in[2];
    const float* W_ih     = (const float*)d_in[3];
    const float* W_hh     = (const float*)d_in[4];
    const float* b_ih     = (const float*)d_in[5];
    const float* b_hh     = (const float*)d_in[6];
    const float* W_out    = (const float*)d_in[7];
    const float* b_out    = (const float*)d_in[8];
    float* out = (float*)d_out;

    // ws layout: [0, 8KB) h exchange buffer (u64[2][512]); [8KB, 8KB+2MB) hs
    unsigned long long* hbuf = (unsigned long long*)d_ws;
    float* hs = (float*)((char*)d_ws + 2 * HIDDEN * sizeof(unsigned long long));

    // reset seq tags every launch (graph-replay determinism)
    hipMemsetAsync(d_ws, 0, 2 * HIDDEN * sizeof(unsigned long long), stream);

    lstm_scan_kernel<<<32, 256, 0, stream>>>(features, captions, emb,
                                             W_ih, W_hh, b_ih, b_hh, hbuf, hs);
    logits_kernel<<<dim3(VOCAB / 64, STEPS / 64), 256, 0, stream>>>(hs, W_out, b_out, out);
    softmax_kernel<<<STEPS, 256, 0, stream>>>(out);
}

// Round 2
// 3933.226 us; speedup vs baseline: 1.3670x; 1.3670x over previous
//
#include <hip/hip_runtime.h>
#include <cstdint>
#include <cstddef>

#define EMBED  256
#define HIDDEN 512
#define VOCAB  32000
#define BATCH  16
#define TCAP   63
#define STEPS  1024   // BATCH * (TCAP + 1)

// ws layout (bytes)
#define WS_HBUF 0           // float[2][512]        (4 KB)
#define WS_CNT  4096        // u32 lines[16][16]    (1 KB)
#define WS_HS32 8192        // float[1024][512]     (2 MB)
#define WS_HSBF 2105344     // bf16 [1024][512]     (1 MB)
#define WS_WB   3153920     // bf16 [32000][512]    (32 MB)
#define WS_NEED 35921920ull

typedef __bf16 bf16x8 __attribute__((ext_vector_type(8)));
typedef float  f32x4  __attribute__((ext_vector_type(4)));

// ---------------------------------------------------------------------------
// helpers
// ---------------------------------------------------------------------------
__device__ __forceinline__ float sigmoid_f(float x) {
    return 1.0f / (1.0f + __expf(-x));
}
__device__ __forceinline__ float tanh_f(float x) {
    float a = fabsf(x);
    float e = __expf(-2.0f * a);
    float r = (1.0f - e) / (1.0f + e);
    return copysignf(r, x);
}
__device__ __forceinline__ float sel4(float a0, float a1, float a2, float a3, int j) {
    float lo = (j & 1) ? a1 : a0;
    float hi = (j & 1) ? a3 : a2;
    return (j & 2) ? hi : lo;
}
__device__ __forceinline__ unsigned short f2bf_u16(float f) {
    union { float f; unsigned u; } v; v.f = f;
    unsigned r = v.u + 0x7fffu + ((v.u >> 16) & 1u);
    return (unsigned short)(r >> 16);
}

// ---------------------------------------------------------------------------
// Kernel 1: persistent sequential LSTM scan, counter-barrier exchange.
// 32 WGs x 256 threads = 128 waves. Wave w owns h elements [4w, 4w+4).
// Weights in VGPRs. Per step: poll 8-way-replicated WG-counter (1 line per
// replica), acquire fence, plain float4 h reads, FMA, fold-reduce (20
// shuffles), cell update, publish h via relaxed agent atomic float stores,
// __syncthreads, one release fetch_add per WG.
// hbuf/cnt must be zeroed before launch (version 0 == zeros, targets == 0).
// ---------------------------------------------------------------------------
__global__ __launch_bounds__(256, 1) void lstm_scan_kernel(
    const float* __restrict__ features,
    const int*   __restrict__ captions,
    const float* __restrict__ emb,
    const float* __restrict__ W_ih,
    const float* __restrict__ W_hh,
    const float* __restrict__ b_ih,
    const float* __restrict__ b_hh,
    float*    __restrict__ hbuf,   // [2][HIDDEN]
    unsigned* __restrict__ cnt,    // 16 lines x 16 u32
    float*    __restrict__ hs32,   // [STEPS][HIDDEN]
    __bf16*   __restrict__ hsbf,   // [STEPS][HIDDEN] (optional)
    const int wbf)
{
    const int tid = threadIdx.x;
    const int rg  = tid >> 6;
    const int kc  = tid & 63;
    const int w   = blockIdx.x * 4 + rg;   // global wave 0..127
    const int j0  = w * 4;

    // lane -> (gate, elem) ownership after fold: e(l) = 8b0+4b1+2b2+b3
    const int t_own  = ((kc & 1) << 1) | ((kc >> 1) & 1);
    const int jj_own = (((kc >> 2) & 1) << 1) | ((kc >> 3) & 1);

    // ---- weights into registers ----
    float Whh[4][4][8];   // [gate][elem][k-chunk]  k = kc*8 + kk
    float Wih[4][4][4];   // [gate][elem][k-chunk]  k = kc*4 + kk
#pragma unroll
    for (int t = 0; t < 4; ++t) {
#pragma unroll
        for (int jj = 0; jj < 4; ++jj) {
            const int row = t * HIDDEN + j0 + jj;
            const float4* ph = (const float4*)(W_hh + (size_t)row * HIDDEN + kc * 8);
            float4 h0 = ph[0], h1 = ph[1];
            Whh[t][jj][0] = h0.x; Whh[t][jj][1] = h0.y; Whh[t][jj][2] = h0.z; Whh[t][jj][3] = h0.w;
            Whh[t][jj][4] = h1.x; Whh[t][jj][5] = h1.y; Whh[t][jj][6] = h1.z; Whh[t][jj][7] = h1.w;
            const float4 i0 = *(const float4*)(W_ih + (size_t)row * EMBED + kc * 4);
            Wih[t][jj][0] = i0.x; Wih[t][jj][1] = i0.y; Wih[t][jj][2] = i0.z; Wih[t][jj][3] = i0.w;
        }
    }
    // per-lane biases for the 4 gates of MY element
    float b4[4];
#pragma unroll
    for (int t = 0; t < 4; ++t)
        b4[t] = b_ih[t * HIDDEN + j0 + jj_own] + b_hh[t * HIDDEN + j0 + jj_own];

    float c_state = 0.0f;

    float xr[4];
    {
        const float4 v = *(const float4*)(features + kc * 4);
        xr[0] = v.x; xr[1] = v.y; xr[2] = v.z; xr[3] = v.w;
    }

    const int myrep = blockIdx.x & 7;

    for (int s = 0; s < STEPS; ++s) {
        // ---- prefetch next x (independent of h) ----
        float xn[4] = {0.f, 0.f, 0.f, 0.f};
        if (s + 1 < STEPS) {
            const int sb = (s + 1) >> 6, st = (s + 1) & 63;
            const float* xp = (st == 0)
                ? (features + (size_t)sb * EMBED)
                : (emb + (size_t)captions[sb * TCAP + st - 1] * EMBED);
            const float4 v = *(const float4*)(xp + kc * 4);
            xn[0] = v.x; xn[1] = v.y; xn[2] = v.z; xn[3] = v.w;
        }

        // ---- x contribution (before the wait) ----
        float acc[16];
#pragma unroll
        for (int t = 0; t < 4; ++t) {
#pragma unroll
            for (int jj = 0; jj < 4; ++jj) {
                float a = Wih[t][jj][0] * xr[0];
                a = fmaf(Wih[t][jj][1], xr[1], a);
                a = fmaf(Wih[t][jj][2], xr[2], a);
                a = fmaf(Wih[t][jj][3], xr[3], a);
                acc[t * 4 + jj] = a;
            }
        }

        // ---- wait for h version s: poll replicated counter (1 line/replica) ----
        const int p = s & 1;
        const unsigned target = (unsigned)(((s + 1) >> 1) * 4);  // 4 WGs per replica
        if (target) {
            const unsigned* cline = cnt + (size_t)(p * 8 + (kc & 7)) * 16;
            for (;;) {
                const unsigned v = __hip_atomic_load(cline, __ATOMIC_RELAXED,
                                                     __HIP_MEMORY_SCOPE_AGENT);
                if (__all((int)(v >= target))) break;
            }
        }
        __builtin_amdgcn_fence(__ATOMIC_ACQUIRE, "agent");

        // ---- read h once (plain vector loads, fresh after fence) ----
        float hreg[8];
        {
            const float4* hp = (const float4*)(hbuf + (size_t)p * HIDDEN + kc * 8);
            const float4 a = hp[0], b = hp[1];
            hreg[0] = a.x; hreg[1] = a.y; hreg[2] = a.z; hreg[3] = a.w;
            hreg[4] = b.x; hreg[5] = b.y; hreg[6] = b.z; hreg[7] = b.w;
        }

        // ---- h contribution ----
#pragma unroll
        for (int t = 0; t < 4; ++t) {
#pragma unroll
            for (int jj = 0; jj < 4; ++jj) {
                float a = acc[t * 4 + jj];
#pragma unroll
                for (int kk = 0; kk < 8; ++kk)
                    a = fmaf(Whh[t][jj][kk], hreg[kk], a);
                acc[t * 4 + jj] = a;
            }
        }

        // ---- fold-reduce: 16 values x 64 lanes -> 1 full sum per lane ----
#pragma unroll
        for (int i = 0; i < 8; ++i) {
            const float send = (kc & 1) ? acc[i] : acc[i + 8];
            const float keep = (kc & 1) ? acc[i + 8] : acc[i];
            acc[i] = keep + __shfl_xor(send, 1, 64);
        }
#pragma unroll
        for (int i = 0; i < 4; ++i) {
            const float send = (kc & 2) ? acc[i] : acc[i + 4];
            const float keep = (kc & 2) ? acc[i + 4] : acc[i];
            acc[i] = keep + __shfl_xor(send, 2, 64);
        }
#pragma unroll
        for (int i = 0; i < 2; ++i) {
            const float send = (kc & 4) ? acc[i] : acc[i + 2];
            const float keep = (kc & 4) ? acc[i + 2] : acc[i];
            acc[i] = keep + __shfl_xor(send, 4, 64);
        }
        {
            const float send = (kc & 8) ? acc[0] : acc[1];
            const float keep = (kc & 8) ? acc[1] : acc[0];
            acc[0] = keep + __shfl_xor(send, 8, 64);
        }
        float a = acc[0];
        a += __shfl_xor(a, 16, 64);
        a += __shfl_xor(a, 32, 64);
        // lane now holds full gate-sum for element e = (t_own, jj_own)

        // ---- gather the 4 gates of MY element (vary lane bits 0,1) ----
        const float g00 = a;
        const float g01 = __shfl_xor(a, 1, 64);    // t_own ^ 2
        const float g10 = __shfl_xor(a, 2, 64);    // t_own ^ 1
        const float g11 = __shfl_xor(g01, 2, 64);  // t_own ^ 3
        float gi = sel4(g00, g10, g01, g11, t_own)     + b4[0];
        float gf = sel4(g00, g10, g01, g11, t_own ^ 1) + b4[1];
        float gg = sel4(g00, g10, g01, g11, t_own ^ 2) + b4[2];
        float go = sel4(g00, g10, g01, g11, t_own ^ 3) + b4[3];

        gi = sigmoid_f(gi);
        gf = sigmoid_f(gf);
        gg = tanh_f(gg);
        go = sigmoid_f(go);
        c_state = gf * c_state + gi * gg;
        const float hnew = go * tanh_f(c_state);

        // ---- publish: lanes 0,4,8,12 own distinct elements ----
        const int q = (s + 1) & 1;
        if ((kc & 0x33) == 0) {
            const int j = j0 + jj_own;
            __hip_atomic_store(hbuf + (size_t)q * HIDDEN + j, hnew,
                               __ATOMIC_RELAXED, __HIP_MEMORY_SCOPE_AGENT);
            hs32[(size_t)s * HIDDEN + j] = hnew;
            if (wbf) hsbf[(size_t)s * HIDDEN + j] = (__bf16)hnew;
        }
        __syncthreads();
        if (tid == 0)
            __hip_atomic_fetch_add(cnt + (size_t)(q * 8 + myrep) * 16, 1u,
                                   __ATOMIC_RELEASE, __HIP_MEMORY_SCOPE_AGENT);

        xr[0] = xn[0]; xr[1] = xn[1]; xr[2] = xn[2]; xr[3] = xn[3];
    }
}

// ---------------------------------------------------------------------------
// Kernel 2a: W_out fp32 -> bf16 conversion (grid-stride, vectorized).
// ---------------------------------------------------------------------------
__global__ __launch_bounds__(256) void convert_w_kernel(
    const float* __restrict__ W, unsigned short* __restrict__ Wb, int n)
{
    const int stride = gridDim.x * blockDim.x * 4;
    for (int i = (blockIdx.x * blockDim.x + threadIdx.x) * 4; i < n; i += stride) {
        const float4 v = *(const float4*)(W + i);
        ushort4 o;
        o.x = f2bf_u16(v.x); o.y = f2bf_u16(v.y);
        o.z = f2bf_u16(v.z); o.w = f2bf_u16(v.w);
        *(ushort4*)(Wb + i) = o;
    }
}

// ---------------------------------------------------------------------------
// Kernel 2b: logits = hs_bf16 @ Wb^T + b_out via MFMA (M=1024,N=32000,K=512).
// 128x128 tile, BK=64, 4 waves (2x2), 16x16x32 bf16 MFMA, XOR-swizzled LDS.
// ---------------------------------------------------------------------------
__global__ __launch_bounds__(256) void logits_mfma_kernel(
    const __bf16* __restrict__ A,    // [1024][512]
    const __bf16* __restrict__ B,    // [32000][512]
    const float* __restrict__ b_out,
    float* __restrict__ out)
{
    __shared__ char AsR[16384];
    __shared__ char BsR[16384];
    const int tid  = threadIdx.x;
    const int lane = tid & 63;
    const int wave = tid >> 6;
    const int wm = (wave >> 1) * 64;
    const int wn = (wave & 1) * 64;
    const int n0 = blockIdx.x * 128;
    const int m0 = blockIdx.y * 128;

    f32x4 acc[4][4] = {};

    for (int k0 = 0; k0 < HIDDEN; k0 += 64) {
        if (k0) __syncthreads();
#pragma unroll
        for (int i = 0; i < 4; ++i) {
            const int o   = (tid + i * 256) << 4;      // LDS byte offset
            const int row = o >> 7;                    // 0..127
            const int cb  = o & 127;                   // byte col (16-aligned)
            const int sc  = cb ^ ((row & 7) << 4);     // swizzled
            const bf16x8 av = *(const bf16x8*)(A + (size_t)(m0 + row) * HIDDEN + k0 + (cb >> 1));
            const bf16x8 bv = *(const bf16x8*)(B + (size_t)(n0 + row) * HIDDEN + k0 + (cb >> 1));
            *(bf16x8*)(AsR + row * 128 + sc) = av;
            *(bf16x8*)(BsR + row * 128 + sc) = bv;
        }
        __syncthreads();
#pragma unroll
        for (int ks = 0; ks < 2; ++ks) {
            const int kb = ks * 64 + ((lane >> 4) << 4);   // byte offset of k slice
            bf16x8 af[4], bfr[4];
#pragma unroll
            for (int mi = 0; mi < 4; ++mi) {
                const int r = wm + mi * 16 + (lane & 15);
                af[mi] = *(const bf16x8*)(AsR + r * 128 + (kb ^ ((r & 7) << 4)));
            }
#pragma unroll
            for (int ni = 0; ni < 4; ++ni) {
                const int r = wn + ni * 16 + (lane & 15);
                bfr[ni] = *(const bf16x8*)(BsR + r * 128 + (kb ^ ((r & 7) << 4)));
            }
#pragma unroll
            for (int mi = 0; mi < 4; ++mi)
#pragma unroll
                for (int ni = 0; ni < 4; ++ni)
                    acc[mi][ni] = __builtin_amdgcn_mfma_f32_16x16x32_bf16(
                        af[mi], bfr[ni], acc[mi][ni], 0, 0, 0);
        }
    }

#pragma unroll
    for (int ni = 0; ni < 4; ++ni) {
        const int col = n0 + wn + ni * 16 + (lane & 15);
        const float bo = b_out[col];
#pragma unroll
        for (int mi = 0; mi < 4; ++mi) {
            const int r0 = m0 + wm + mi * 16 + ((lane >> 4) << 2);
#pragma unroll
            for (int qq = 0; qq < 4; ++qq)
                out[(size_t)(r0 + qq) * VOCAB + col] = acc[mi][ni][qq] + bo;
        }
    }
}

// ---------------------------------------------------------------------------
// Kernel 2-fallback: fp32 vector GEMM (round-1, known good).
// ---------------------------------------------------------------------------
__global__ __launch_bounds__(256) void logits_kernel(
    const float* __restrict__ hs,
    const float* __restrict__ W_out,
    const float* __restrict__ b_out,
    float* __restrict__ out)
{
    __shared__ float As[64][65];
    __shared__ float Bs[64][65];
    const int tid = threadIdx.x;
    const int tx = tid & 15, ty = tid >> 4;
    const int v0 = blockIdx.x * 64;
    const int s0 = blockIdx.y * 64;
    float accv[4][4] = {};

    for (int k0 = 0; k0 < HIDDEN; k0 += 64) {
#pragma unroll
        for (int i = 0; i < 4; ++i) {
            const int idx = tid + i * 256;
            const int r = idx >> 4, q = idx & 15;
            const float4 a = *(const float4*)(hs + (size_t)(s0 + r) * HIDDEN + k0 + q * 4);
            As[r][q * 4 + 0] = a.x; As[r][q * 4 + 1] = a.y;
            As[r][q * 4 + 2] = a.z; As[r][q * 4 + 3] = a.w;
            const float4 b = *(const float4*)(W_out + (size_t)(v0 + r) * HIDDEN + k0 + q * 4);
            Bs[r][q * 4 + 0] = b.x; Bs[r][q * 4 + 1] = b.y;
            Bs[r][q * 4 + 2] = b.z; Bs[r][q * 4 + 3] = b.w;
        }
        __syncthreads();
#pragma unroll 16
        for (int kk = 0; kk < 64; ++kk) {
            float av[4], bv[4];
#pragma unroll
            for (int i = 0; i < 4; ++i) av[i] = As[ty * 4 + i][kk];
#pragma unroll
            for (int j = 0; j < 4; ++j) bv[j] = Bs[tx * 4 + j][kk];
#pragma unroll
            for (int i = 0; i < 4; ++i)
#pragma unroll
                for (int j = 0; j < 4; ++j)
                    accv[i][j] = fmaf(av[i], bv[j], accv[i][j]);
        }
        __syncthreads();
    }
#pragma unroll
    for (int i = 0; i < 4; ++i) {
        const int s = s0 + ty * 4 + i;
#pragma unroll
        for (int j = 0; j < 4; ++j) {
            const int v = v0 + tx * 4 + j;
            out[(size_t)s * VOCAB + v] = accv[i][j] + b_out[v];
        }
    }
}

// ---------------------------------------------------------------------------
// Kernel 3: in-place row softmax, one WG (256 threads) per row of 32000.
// ---------------------------------------------------------------------------
__global__ __launch_bounds__(256) void softmax_kernel(float* __restrict__ out)
{
    const int row = blockIdx.x;
    float* p = out + (size_t)row * VOCAB;
    const int tid = threadIdx.x;
    __shared__ float redm[4];
    __shared__ float reds[4];

    float m = -3.402823466e38f;
    for (int idx = tid * 4; idx < VOCAB; idx += 1024) {
        const float4 v = *(const float4*)(p + idx);
        m = fmaxf(m, fmaxf(fmaxf(v.x, v.y), fmaxf(v.z, v.w)));
    }
#pragma unroll
    for (int d = 1; d < 64; d <<= 1) m = fmaxf(m, __shfl_xor(m, d, 64));
    if ((tid & 63) == 0) redm[tid >> 6] = m;
    __syncthreads();
    m = fmaxf(fmaxf(redm[0], redm[1]), fmaxf(redm[2], redm[3]));

    float sum = 0.f;
    for (int idx = tid * 4; idx < VOCAB; idx += 1024) {
        const float4 v = *(const float4*)(p + idx);
        sum += __expf(v.x - m) + __expf(v.y - m) + __expf(v.z - m) + __expf(v.w - m);
    }
#pragma unroll
    for (int d = 1; d < 64; d <<= 1) sum += __shfl_xor(sum, d, 64);
    if ((tid & 63) == 0) reds[tid >> 6] = sum;
    __syncthreads();
    sum = reds[0] + reds[1] + reds[2] + reds[3];
    const float inv = 1.0f / sum;

    for (int idx = tid * 4; idx < VOCAB; idx += 1024) {
        const float4 v = *(const float4*)(p + idx);
        float4 o;
        o.x = __expf(v.x - m) * inv;
        o.y = __expf(v.y - m) * inv;
        o.z = __expf(v.z - m) * inv;
        o.w = __expf(v.w - m) * inv;
        *(float4*)(p + idx) = o;
    }
}

// ---------------------------------------------------------------------------
// launch
// ---------------------------------------------------------------------------
extern "C" void kernel_launch(void* const* d_in, const int* in_sizes, int n_in,
                              void* d_out, int out_size, void* d_ws, size_t ws_size,
                              hipStream_t stream)
{
    const float* features = (const float*)d_in[0];
    const int*   captions = (const int*)d_in[1];
    const float* emb      = (const float*)d_in[2];
    const float* W_ih     = (const float*)d_in[3];
    const float* W_hh     = (const float*)d_in[4];
    const float* b_ih     = (const float*)d_in[5];
    const float* b_hh     = (const float*)d_in[6];
    const float* W_out    = (const float*)d_in[7];
    const float* b_out    = (const float*)d_in[8];
    float* out = (float*)d_out;

    char* ws = (char*)d_ws;
    float*    hbuf = (float*)(ws + WS_HBUF);
    unsigned* cnt  = (unsigned*)(ws + WS_CNT);
    float*    hs32 = (float*)(ws + WS_HS32);
    __bf16*   hsbf = (__bf16*)(ws + WS_HSBF);
    __bf16*   Wb   = (__bf16*)(ws + WS_WB);
    const bool mfma_ok = ws_size >= WS_NEED;

    // reset h exchange buffer + counters (graph-replay determinism)
    hipMemsetAsync(d_ws, 0, 5120, stream);

    if (mfma_ok) {
        convert_w_kernel<<<2048, 256, 0, stream>>>(W_out, (unsigned short*)Wb,
                                                   VOCAB * HIDDEN);
        lstm_scan_kernel<<<32, 256, 0, stream>>>(features, captions, emb,
                                                 W_ih, W_hh, b_ih, b_hh,
                                                 hbuf, cnt, hs32, hsbf, 1);
        logits_mfma_kernel<<<dim3(VOCAB / 128, STEPS / 128), 256, 0, stream>>>(
            hsbf, Wb, b_out, out);
    } else {
        lstm_scan_kernel<<<32, 256, 0, stream>>>(features, captions, emb,
                                                 W_ih, W_hh, b_ih, b_hh,
                                                 hbuf, cnt, hs32, hsbf, 0);
        logits_kernel<<<dim3(VOCAB / 64, STEPS / 64), 256, 0, stream>>>(
            hs32, W_out, b_out, out);
    }
    softmax_kernel<<<STEPS, 256, 0, stream>>>(out);
}

// Round 3
// 2897.176 us; speedup vs baseline: 1.8559x; 1.3576x over previous
//
#include <hip/hip_runtime.h>
#include <cstdint>
#include <cstddef>

#define EMBED  256
#define HIDDEN 512
#define VOCAB  32000
#define BATCH  16
#define TCAP   63
#define STEPS  1024   // BATCH * (TCAP + 1)
#define GROWS  2048   // 4 * HIDDEN gate rows

// ws layout (bytes)
#define WS_HBUF  0          // u64 [2][512] tagged h words  (8 KB)
#define WS_FLAGS 8192       // u32 [32] per-WG step flags   (128 B)
#define WS_HS32  12288      // float[1024][512]             (2 MB)
#define WS_HSBF  2109440    // bf16 [1024][512]             (1 MB)
#define WS_WB    3158016    // bf16 [32000][512]            (32 MB); xp overlays first 8 MB
#define WS_NEED  36712448ull

typedef __bf16 bf16x8 __attribute__((ext_vector_type(8)));
typedef float  f32x4  __attribute__((ext_vector_type(4)));

// ---------------------------------------------------------------------------
// helpers
// ---------------------------------------------------------------------------
__device__ __forceinline__ float sigmoid_f(float x) {
    return 1.0f / (1.0f + __expf(-x));
}
__device__ __forceinline__ float tanh_f(float x) {
    float a = fabsf(x);
    float e = __expf(-2.0f * a);
    float r = (1.0f - e) / (1.0f + e);
    return copysignf(r, x);
}
__device__ __forceinline__ float sel4(float a0, float a1, float a2, float a3, int j) {
    float lo = (j & 1) ? a1 : a0;
    float hi = (j & 1) ? a3 : a2;
    return (j & 2) ? hi : lo;
}
__device__ __forceinline__ unsigned short f2bf_u16(float f) {
    union { float f; unsigned u; } v; v.f = f;
    unsigned r = v.u + 0x7fffu + ((v.u >> 16) & 1u);
    return (unsigned short)(r >> 16);
}

// ---------------------------------------------------------------------------
// Kernel 0: xp[s][r] = xs[s] . W_ih[r] + b_ih[r] + b_hh[r]
// xs[s] gathered on the fly (features row or embedding row).
// M=1024 steps, N=2048 gate rows, K=256. 64x64 tiles, 4x4 micro-tile.
// ---------------------------------------------------------------------------
__global__ __launch_bounds__(256) void xproj_kernel(
    const float* __restrict__ features,
    const int*   __restrict__ captions,
    const float* __restrict__ emb,
    const float* __restrict__ W_ih,
    const float* __restrict__ b_ih,
    const float* __restrict__ b_hh,
    float* __restrict__ xp)            // [STEPS][GROWS]
{
    __shared__ float As[64][65];
    __shared__ float Bs[64][65];
    const int tid = threadIdx.x;
    const int tx = tid & 15, ty = tid >> 4;
    const int r0 = blockIdx.x * 64;    // gate-row tile
    const int s0 = blockIdx.y * 64;    // step tile
    float accv[4][4] = {};

    for (int k0 = 0; k0 < EMBED; k0 += 64) {
#pragma unroll
        for (int i = 0; i < 4; ++i) {
            const int idx = tid + i * 256;
            const int row = idx >> 4, q = idx & 15;
            const int s = s0 + row, sb = s >> 6, st = s & 63;
            const float* xr = (st == 0)
                ? (features + (size_t)sb * EMBED)
                : (emb + (size_t)captions[sb * TCAP + st - 1] * EMBED);
            const float4 a = *(const float4*)(xr + k0 + q * 4);
            As[row][q * 4 + 0] = a.x; As[row][q * 4 + 1] = a.y;
            As[row][q * 4 + 2] = a.z; As[row][q * 4 + 3] = a.w;
            const float4 b = *(const float4*)(W_ih + (size_t)(r0 + row) * EMBED + k0 + q * 4);
            Bs[row][q * 4 + 0] = b.x; Bs[row][q * 4 + 1] = b.y;
            Bs[row][q * 4 + 2] = b.z; Bs[row][q * 4 + 3] = b.w;
        }
        __syncthreads();
#pragma unroll 16
        for (int kk = 0; kk < 64; ++kk) {
            float av[4], bv[4];
#pragma unroll
            for (int i = 0; i < 4; ++i) av[i] = As[ty * 4 + i][kk];
#pragma unroll
            for (int j = 0; j < 4; ++j) bv[j] = Bs[tx * 4 + j][kk];
#pragma unroll
            for (int i = 0; i < 4; ++i)
#pragma unroll
                for (int j = 0; j < 4; ++j)
                    accv[i][j] = fmaf(av[i], bv[j], accv[i][j]);
        }
        __syncthreads();
    }
#pragma unroll
    for (int j = 0; j < 4; ++j) {
        const int r = r0 + tx * 4 + j;
        const float bb = b_ih[r] + b_hh[r];
#pragma unroll
        for (int i = 0; i < 4; ++i)
            xp[(size_t)(s0 + ty * 4 + i) * GROWS + r] = accv[i][j] + bb;
    }
}

// ---------------------------------------------------------------------------
// Kernel 1: persistent sequential LSTM scan. 32 WGs x 4 waves = 128 waves.
// Wave w owns h elements [4w,4w+4) = 16 gate rows; W_hh slice in VGPRs
// (128/lane). Sync protocol (NO fences, relaxed agent atomics only):
//   producer: tagged u64 stores (s+1)<<32|h  -> __syncthreads (drains vmcnt)
//             -> one flag store flags[wg]=s+1
//   consumer: poll flag line (1 coalesced 128B read/wave/round) until all
//             flags >= s, then bulk-read 8 tagged u64, verify tags == s,
//             re-read on mismatch (safety net for store reordering).
// Parity: version v lives in hbuf[v&1]; writer of v+2 has observed all
// flags >= v+1, which implies every wave already consumed version v.
// hbuf+flags must be zeroed before launch (version 0 == zeros, tag 0).
// ---------------------------------------------------------------------------
__global__ __launch_bounds__(256, 1) void lstm_scan_kernel(
    const float* __restrict__ W_hh,
    const float* __restrict__ xp,              // [STEPS][GROWS]
    unsigned long long* __restrict__ hbuf,     // [2][HIDDEN]
    unsigned* __restrict__ flags,              // [32]
    float* __restrict__ hs32,                  // [STEPS][HIDDEN]
    __bf16* __restrict__ hsbf,                 // [STEPS][HIDDEN]
    const int wbf)
{
    const int tid = threadIdx.x;
    const int rg  = tid >> 6;
    const int kc  = tid & 63;
    const int w   = blockIdx.x * 4 + rg;   // global wave 0..127
    const int j0  = w * 4;

    // lane -> (gate, elem) ownership after fold
    const int t_own  = ((kc & 1) << 1) | ((kc >> 1) & 1);
    const int jj_own = (((kc >> 2) & 1) << 1) | ((kc >> 3) & 1);
    const int row_own = t_own * HIDDEN + j0 + jj_own;

    // ---- W_hh slice into registers: 16 rows x 8 k-chunk per lane ----
    float Whh[4][4][8];
#pragma unroll
    for (int t = 0; t < 4; ++t) {
#pragma unroll
        for (int jj = 0; jj < 4; ++jj) {
            const int row = t * HIDDEN + j0 + jj;
            const float4* ph = (const float4*)(W_hh + (size_t)row * HIDDEN + kc * 8);
            const float4 h0 = ph[0], h1 = ph[1];
            Whh[t][jj][0] = h0.x; Whh[t][jj][1] = h0.y; Whh[t][jj][2] = h0.z; Whh[t][jj][3] = h0.w;
            Whh[t][jj][4] = h1.x; Whh[t][jj][5] = h1.y; Whh[t][jj][6] = h1.z; Whh[t][jj][7] = h1.w;
        }
    }

    float c_state = 0.0f;

    for (int s = 0; s < STEPS; ++s) {
        const int p = s & 1;
        const unsigned expect = (unsigned)s;

        // ---- gate: poll per-WG flag line (coalesced, 2 cache lines) ----
        {
            const unsigned* f = flags + (kc & 31);
            for (;;) {
                const unsigned v = __hip_atomic_load(f, __ATOMIC_RELAXED,
                                                     __HIP_MEMORY_SCOPE_AGENT);
                if (__all((int)(v >= expect))) break;
            }
        }

        // ---- xp for my row (independent of h; L2/MALL-resident stream) ----
        const float xpv = xp[(size_t)s * GROWS + row_own];

        // ---- bulk-read h version s, tag-verified ----
        unsigned long long hv[8];
        const unsigned long long* hb = hbuf + (size_t)p * HIDDEN + kc * 8;
        for (;;) {
#pragma unroll
            for (int kk = 0; kk < 8; ++kk)
                hv[kk] = __hip_atomic_load(hb + kk, __ATOMIC_RELAXED,
                                           __HIP_MEMORY_SCOPE_AGENT);
            bool ok = true;
#pragma unroll
            for (int kk = 0; kk < 8; ++kk)
                ok &= ((unsigned)(hv[kk] >> 32) == expect);
            if (__all((int)ok)) break;
        }
        float hreg[8];
#pragma unroll
        for (int kk = 0; kk < 8; ++kk)
            hreg[kk] = __uint_as_float((unsigned)(hv[kk] & 0xffffffffULL));

        // ---- h contribution: 16 rows x 8 k ----
        float acc[16];
#pragma unroll
        for (int t = 0; t < 4; ++t) {
#pragma unroll
            for (int jj = 0; jj < 4; ++jj) {
                float a = Whh[t][jj][0] * hreg[0];
#pragma unroll
                for (int kk = 1; kk < 8; ++kk)
                    a = fmaf(Whh[t][jj][kk], hreg[kk], a);
                acc[t * 4 + jj] = a;
            }
        }

        // ---- fold-reduce 16 x 64 lanes -> full sum per lane ----
#pragma unroll
        for (int i = 0; i < 8; ++i) {
            const float send = (kc & 1) ? acc[i] : acc[i + 8];
            const float keep = (kc & 1) ? acc[i + 8] : acc[i];
            acc[i] = keep + __shfl_xor(send, 1, 64);
        }
#pragma unroll
        for (int i = 0; i < 4; ++i) {
            const float send = (kc & 2) ? acc[i] : acc[i + 4];
            const float keep = (kc & 2) ? acc[i + 4] : acc[i];
            acc[i] = keep + __shfl_xor(send, 2, 64);
        }
#pragma unroll
        for (int i = 0; i < 2; ++i) {
            const float send = (kc & 4) ? acc[i] : acc[i + 2];
            const float keep = (kc & 4) ? acc[i + 2] : acc[i];
            acc[i] = keep + __shfl_xor(send, 4, 64);
        }
        {
            const float send = (kc & 8) ? acc[0] : acc[1];
            const float keep = (kc & 8) ? acc[1] : acc[0];
            acc[0] = keep + __shfl_xor(send, 8, 64);
        }
        float a = acc[0];
        a += __shfl_xor(a, 16, 64);
        a += __shfl_xor(a, 32, 64);
        a += xpv;   // full gate pre-activation for (t_own, jj_own)

        // ---- gather the 4 gates of MY element (lane bits 0,1 vary t_own) ----
        const float g00 = a;
        const float g01 = __shfl_xor(a, 1, 64);    // t_own ^ 2
        const float g10 = __shfl_xor(a, 2, 64);    // t_own ^ 1
        const float g11 = __shfl_xor(g01, 2, 64);  // t_own ^ 3
        float gi = sel4(g00, g10, g01, g11, t_own);
        float gf = sel4(g00, g10, g01, g11, t_own ^ 1);
        float gg = sel4(g00, g10, g01, g11, t_own ^ 2);
        float go = sel4(g00, g10, g01, g11, t_own ^ 3);

        gi = sigmoid_f(gi);
        gf = sigmoid_f(gf);
        gg = tanh_f(gg);
        go = sigmoid_f(go);
        c_state = gf * c_state + gi * gg;
        const float hnew = go * tanh_f(c_state);

        // ---- publish version s+1: lanes 0,4,8,12 own distinct elements ----
        const int q = (s + 1) & 1;
        if ((kc & 0x33) == 0) {
            const int j = j0 + jj_own;
            const unsigned long long pack =
                ((unsigned long long)(unsigned)(s + 1) << 32) |
                (unsigned long long)__float_as_uint(hnew);
            __hip_atomic_store(hbuf + (size_t)q * HIDDEN + j, pack,
                               __ATOMIC_RELAXED, __HIP_MEMORY_SCOPE_AGENT);
            hs32[(size_t)s * HIDDEN + j] = hnew;
            if (wbf) hsbf[(size_t)s * HIDDEN + j] = (__bf16)hnew;
        }
        __syncthreads();   // drains vmcnt: data stores complete before flag
        if (tid == 0)
            __hip_atomic_store(flags + blockIdx.x, (unsigned)(s + 1),
                               __ATOMIC_RELAXED, __HIP_MEMORY_SCOPE_AGENT);
    }
}

// ---------------------------------------------------------------------------
// Kernel 2a: W_out fp32 -> bf16 conversion (runs AFTER scan; overwrites xp).
// ---------------------------------------------------------------------------
__global__ __launch_bounds__(256) void convert_w_kernel(
    const float* __restrict__ W, unsigned short* __restrict__ Wb, int n)
{
    const int stride = gridDim.x * blockDim.x * 4;
    for (int i = (blockIdx.x * blockDim.x + threadIdx.x) * 4; i < n; i += stride) {
        const float4 v = *(const float4*)(W + i);
        ushort4 o;
        o.x = f2bf_u16(v.x); o.y = f2bf_u16(v.y);
        o.z = f2bf_u16(v.z); o.w = f2bf_u16(v.w);
        *(ushort4*)(Wb + i) = o;
    }
}

// ---------------------------------------------------------------------------
// Kernel 2b: logits = hs_bf16 @ Wb^T + b_out via MFMA (M=1024,N=32000,K=512).
// ---------------------------------------------------------------------------
__global__ __launch_bounds__(256) void logits_mfma_kernel(
    const __bf16* __restrict__ A,    // [1024][512]
    const __bf16* __restrict__ B,    // [32000][512]
    const float* __restrict__ b_out,
    float* __restrict__ out)
{
    __shared__ char AsR[16384];
    __shared__ char BsR[16384];
    const int tid  = threadIdx.x;
    const int lane = tid & 63;
    const int wave = tid >> 6;
    const int wm = (wave >> 1) * 64;
    const int wn = (wave & 1) * 64;
    const int n0 = blockIdx.x * 128;
    const int m0 = blockIdx.y * 128;

    f32x4 acc[4][4] = {};

    for (int k0 = 0; k0 < HIDDEN; k0 += 64) {
        if (k0) __syncthreads();
#pragma unroll
        for (int i = 0; i < 4; ++i) {
            const int o   = (tid + i * 256) << 4;
            const int row = o >> 7;
            const int cb  = o & 127;
            const int sc  = cb ^ ((row & 7) << 4);
            const bf16x8 av = *(const bf16x8*)(A + (size_t)(m0 + row) * HIDDEN + k0 + (cb >> 1));
            const bf16x8 bv = *(const bf16x8*)(B + (size_t)(n0 + row) * HIDDEN + k0 + (cb >> 1));
            *(bf16x8*)(AsR + row * 128 + sc) = av;
            *(bf16x8*)(BsR + row * 128 + sc) = bv;
        }
        __syncthreads();
#pragma unroll
        for (int ks = 0; ks < 2; ++ks) {
            const int kb = ks * 64 + ((lane >> 4) << 4);
            bf16x8 af[4], bfr[4];
#pragma unroll
            for (int mi = 0; mi < 4; ++mi) {
                const int r = wm + mi * 16 + (lane & 15);
                af[mi] = *(const bf16x8*)(AsR + r * 128 + (kb ^ ((r & 7) << 4)));
            }
#pragma unroll
            for (int ni = 0; ni < 4; ++ni) {
                const int r = wn + ni * 16 + (lane & 15);
                bfr[ni] = *(const bf16x8*)(BsR + r * 128 + (kb ^ ((r & 7) << 4)));
            }
#pragma unroll
            for (int mi = 0; mi < 4; ++mi)
#pragma unroll
                for (int ni = 0; ni < 4; ++ni)
                    acc[mi][ni] = __builtin_amdgcn_mfma_f32_16x16x32_bf16(
                        af[mi], bfr[ni], acc[mi][ni], 0, 0, 0);
        }
    }

#pragma unroll
    for (int ni = 0; ni < 4; ++ni) {
        const int col = n0 + wn + ni * 16 + (lane & 15);
        const float bo = b_out[col];
#pragma unroll
        for (int mi = 0; mi < 4; ++mi) {
            const int r0 = m0 + wm + mi * 16 + ((lane >> 4) << 2);
#pragma unroll
            for (int qq = 0; qq < 4; ++qq)
                out[(size_t)(r0 + qq) * VOCAB + col] = acc[mi][ni][qq] + bo;
        }
    }
}

// ---------------------------------------------------------------------------
// Kernel 2-fallback: fp32 vector GEMM.
// ---------------------------------------------------------------------------
__global__ __launch_bounds__(256) void logits_kernel(
    const float* __restrict__ hs,
    const float* __restrict__ W_out,
    const float* __restrict__ b_out,
    float* __restrict__ out)
{
    __shared__ float As[64][65];
    __shared__ float Bs[64][65];
    const int tid = threadIdx.x;
    const int tx = tid & 15, ty = tid >> 4;
    const int v0 = blockIdx.x * 64;
    const int s0 = blockIdx.y * 64;
    float accv[4][4] = {};

    for (int k0 = 0; k0 < HIDDEN; k0 += 64) {
#pragma unroll
        for (int i = 0; i < 4; ++i) {
            const int idx = tid + i * 256;
            const int r = idx >> 4, q = idx & 15;
            const float4 a = *(const float4*)(hs + (size_t)(s0 + r) * HIDDEN + k0 + q * 4);
            As[r][q * 4 + 0] = a.x; As[r][q * 4 + 1] = a.y;
            As[r][q * 4 + 2] = a.z; As[r][q * 4 + 3] = a.w;
            const float4 b = *(const float4*)(W_out + (size_t)(v0 + r) * HIDDEN + k0 + q * 4);
            Bs[r][q * 4 + 0] = b.x; Bs[r][q * 4 + 1] = b.y;
            Bs[r][q * 4 + 2] = b.z; Bs[r][q * 4 + 3] = b.w;
        }
        __syncthreads();
#pragma unroll 16
        for (int kk = 0; kk < 64; ++kk) {
            float av[4], bv[4];
#pragma unroll
            for (int i = 0; i < 4; ++i) av[i] = As[ty * 4 + i][kk];
#pragma unroll
            for (int j = 0; j < 4; ++j) bv[j] = Bs[tx * 4 + j][kk];
#pragma unroll
            for (int i = 0; i < 4; ++i)
#pragma unroll
                for (int j = 0; j < 4; ++j)
                    accv[i][j] = fmaf(av[i], bv[j], accv[i][j]);
        }
        __syncthreads();
    }
#pragma unroll
    for (int i = 0; i < 4; ++i) {
        const int s = s0 + ty * 4 + i;
#pragma unroll
        for (int j = 0; j < 4; ++j) {
            const int v = v0 + tx * 4 + j;
            out[(size_t)s * VOCAB + v] = accv[i][j] + b_out[v];
        }
    }
}

// ---------------------------------------------------------------------------
// Kernel 3: in-place row softmax, one WG per row of 32000.
// ---------------------------------------------------------------------------
__global__ __launch_bounds__(256) void softmax_kernel(float* __restrict__ out)
{
    const int row = blockIdx.x;
    float* p = out + (size_t)row * VOCAB;
    const int tid = threadIdx.x;
    __shared__ float redm[4];
    __shared__ float reds[4];

    float m = -3.402823466e38f;
    for (int idx = tid * 4; idx < VOCAB; idx += 1024) {
        const float4 v = *(const float4*)(p + idx);
        m = fmaxf(m, fmaxf(fmaxf(v.x, v.y), fmaxf(v.z, v.w)));
    }
#pragma unroll
    for (int d = 1; d < 64; d <<= 1) m = fmaxf(m, __shfl_xor(m, d, 64));
    if ((tid & 63) == 0) redm[tid >> 6] = m;
    __syncthreads();
    m = fmaxf(fmaxf(redm[0], redm[1]), fmaxf(redm[2], redm[3]));

    float sum = 0.f;
    for (int idx = tid * 4; idx < VOCAB; idx += 1024) {
        const float4 v = *(const float4*)(p + idx);
        sum += __expf(v.x - m) + __expf(v.y - m) + __expf(v.z - m) + __expf(v.w - m);
    }
#pragma unroll
    for (int d = 1; d < 64; d <<= 1) sum += __shfl_xor(sum, d, 64);
    if ((tid & 63) == 0) reds[tid >> 6] = sum;
    __syncthreads();
    sum = reds[0] + reds[1] + reds[2] + reds[3];
    const float inv = 1.0f / sum;

    for (int idx = tid * 4; idx < VOCAB; idx += 1024) {
        const float4 v = *(const float4*)(p + idx);
        float4 o;
        o.x = __expf(v.x - m) * inv;
        o.y = __expf(v.y - m) * inv;
        o.z = __expf(v.z - m) * inv;
        o.w = __expf(v.w - m) * inv;
        *(float4*)(p + idx) = o;
    }
}

// ---------------------------------------------------------------------------
// launch:  memset sync area -> xproj -> scan -> convert -> logits -> softmax
// ---------------------------------------------------------------------------
extern "C" void kernel_launch(void* const* d_in, const int* in_sizes, int n_in,
                              void* d_out, int out_size, void* d_ws, size_t ws_size,
                              hipStream_t stream)
{
    const float* features = (const float*)d_in[0];
    const int*   captions = (const int*)d_in[1];
    const float* emb      = (const float*)d_in[2];
    const float* W_ih     = (const float*)d_in[3];
    const float* W_hh     = (const float*)d_in[4];
    const float* b_ih     = (const float*)d_in[5];
    const float* b_hh     = (const float*)d_in[6];
    const float* W_out    = (const float*)d_in[7];
    const float* b_out    = (const float*)d_in[8];
    float* out = (float*)d_out;

    char* ws = (char*)d_ws;
    unsigned long long* hbuf  = (unsigned long long*)(ws + WS_HBUF);
    unsigned*           flags = (unsigned*)(ws + WS_FLAGS);
    float*              hs32  = (float*)(ws + WS_HS32);
    __bf16*             hsbf  = (__bf16*)(ws + WS_HSBF);
    __bf16*             Wb    = (__bf16*)(ws + WS_WB);
    const bool mfma_ok = ws_size >= WS_NEED;
    // xp overlays Wb's first 8 MB (dead until convert, which runs after scan);
    // fallback places xp over the unused hsbf region.
    float* xpb = mfma_ok ? (float*)(ws + WS_WB) : (float*)(ws + WS_HSBF);

    // reset tagged h words + flags (graph-replay determinism)
    hipMemsetAsync(d_ws, 0, 8320, stream);

    xproj_kernel<<<dim3(GROWS / 64, STEPS / 64), 256, 0, stream>>>(
        features, captions, emb, W_ih, b_ih, b_hh, xpb);
    lstm_scan_kernel<<<32, 256, 0, stream>>>(W_hh, xpb, hbuf, flags,
                                             hs32, hsbf, mfma_ok ? 1 : 0);
    if (mfma_ok) {
        convert_w_kernel<<<2048, 256, 0, stream>>>(W_out, (unsigned short*)Wb,
                                                   VOCAB * HIDDEN);
        logits_mfma_kernel<<<dim3(VOCAB / 128, STEPS / 128), 256, 0, stream>>>(
            hsbf, Wb, b_out, out);
    } else {
        logits_kernel<<<dim3(VOCAB / 64, STEPS / 64), 256, 0, stream>>>(
            hs32, W_out, b_out, out);
    }
    softmax_kernel<<<STEPS, 256, 0, stream>>>(out);
}

// Round 4
// 2170.182 us; speedup vs baseline: 2.4776x; 1.3350x over previous
//
#include <hip/hip_runtime.h>
#include <cstdint>
#include <cstddef>

#define EMBED  256
#define HIDDEN 512
#define VOCAB  32000
#define BATCH  16
#define TCAP   63
#define STEPS  1024   // BATCH * (TCAP + 1)
#define GROWS  2048   // 4 * HIDDEN gate rows

// ws layout (bytes)
#define WS_HBUF  0          // u64 [2][512] tagged h words  (8 KB)
#define WS_HS32  8192       // float[1024][512]             (2 MB)
#define WS_HSBF  2105344    // bf16 [1024][512]             (1 MB)
#define WS_WB    3153920    // bf16 [32000][512]            (32 MB)
#define WS_XPOFF (24u * 1024u * 1024u)     // xp lives in Wb's tail 8 MB
#define WS_NEED  36708352ull
// Wb elements protected by xp overlay: [12582912, 16384000)
#define WB_HEAD_ELEMS 12582912

typedef __bf16 bf16x8 __attribute__((ext_vector_type(8)));
typedef float  f32x4  __attribute__((ext_vector_type(4)));

// ---------------------------------------------------------------------------
// helpers
// ---------------------------------------------------------------------------
__device__ __forceinline__ float sigmoid_f(float x) {
    return 1.0f / (1.0f + __expf(-x));
}
__device__ __forceinline__ float tanh_f(float x) {
    float a = fabsf(x);
    float e = __expf(-2.0f * a);
    float r = (1.0f - e) / (1.0f + e);
    return copysignf(r, x);
}
__device__ __forceinline__ float sel4(float a0, float a1, float a2, float a3, int j) {
    float lo = (j & 1) ? a1 : a0;
    float hi = (j & 1) ? a3 : a2;
    return (j & 2) ? hi : lo;
}
__device__ __forceinline__ unsigned short f2bf_u16(float f) {
    union { float f; unsigned u; } v; v.f = f;
    unsigned r = v.u + 0x7fffu + ((v.u >> 16) & 1u);
    return (unsigned short)(r >> 16);
}

// ---------------------------------------------------------------------------
// Kernel 0: xp[s][r] = xs[s] . W_ih[r] + b_ih[r] + b_hh[r]
// ---------------------------------------------------------------------------
__global__ __launch_bounds__(256) void xproj_kernel(
    const float* __restrict__ features,
    const int*   __restrict__ captions,
    const float* __restrict__ emb,
    const float* __restrict__ W_ih,
    const float* __restrict__ b_ih,
    const float* __restrict__ b_hh,
    float* __restrict__ xp)            // [STEPS][GROWS]
{
    __shared__ float As[64][65];
    __shared__ float Bs[64][65];
    const int tid = threadIdx.x;
    const int tx = tid & 15, ty = tid >> 4;
    const int r0 = blockIdx.x * 64;
    const int s0 = blockIdx.y * 64;
    float accv[4][4] = {};

    for (int k0 = 0; k0 < EMBED; k0 += 64) {
#pragma unroll
        for (int i = 0; i < 4; ++i) {
            const int idx = tid + i * 256;
            const int row = idx >> 4, q = idx & 15;
            const int s = s0 + row, sb = s >> 6, st = s & 63;
            const float* xr = (st == 0)
                ? (features + (size_t)sb * EMBED)
                : (emb + (size_t)captions[sb * TCAP + st - 1] * EMBED);
            const float4 a = *(const float4*)(xr + k0 + q * 4);
            As[row][q * 4 + 0] = a.x; As[row][q * 4 + 1] = a.y;
            As[row][q * 4 + 2] = a.z; As[row][q * 4 + 3] = a.w;
            const float4 b = *(const float4*)(W_ih + (size_t)(r0 + row) * EMBED + k0 + q * 4);
            Bs[row][q * 4 + 0] = b.x; Bs[row][q * 4 + 1] = b.y;
            Bs[row][q * 4 + 2] = b.z; Bs[row][q * 4 + 3] = b.w;
        }
        __syncthreads();
#pragma unroll 16
        for (int kk = 0; kk < 64; ++kk) {
            float av[4], bv[4];
#pragma unroll
            for (int i = 0; i < 4; ++i) av[i] = As[ty * 4 + i][kk];
#pragma unroll
            for (int j = 0; j < 4; ++j) bv[j] = Bs[tx * 4 + j][kk];
#pragma unroll
            for (int i = 0; i < 4; ++i)
#pragma unroll
                for (int j = 0; j < 4; ++j)
                    accv[i][j] = fmaf(av[i], bv[j], accv[i][j]);
        }
        __syncthreads();
    }
#pragma unroll
    for (int j = 0; j < 4; ++j) {
        const int r = r0 + tx * 4 + j;
        const float bb = b_ih[r] + b_hh[r];
#pragma unroll
        for (int i = 0; i < 4; ++i)
            xp[(size_t)(s0 + ty * 4 + i) * GROWS + r] = accv[i][j] + bb;
    }
}

// ---------------------------------------------------------------------------
// Kernel 1: persistent sequential LSTM scan + embedded W_out converter.
// WGs 0..31: scan (128 waves own 4 h elements each, W_hh in VGPRs).
// WGs 32..255: convert W_out[0..WB_HEAD_ELEMS) fp32->bf16 on idle CUs.
//
// Scan sync protocol (relaxed agent atomics ONLY, no fences, no flags):
//   producer lane: one tagged u64 store (s+1)<<32 | h_bits.  Immediately.
//   consumer: 4 waves each poll a distinct quarter (2 u64/lane, tag==s),
//             s_sleep(1) backoff on retry, write floats into LDS
//             hlds[s&1][..], ONE __syncthreads, all lanes read h from LDS.
// Slot-reuse safety: any wave that published version s+1 has already read
// version s from global; a writer of version s+2 (same slot as s) consumed
// ALL of version s+1 => every wave finished its global read of version s.
// hbuf must be zeroed before launch (version 0 == zeros, tag 0).
// ---------------------------------------------------------------------------
__global__ __launch_bounds__(256, 1) void lstm_scan_kernel(
    const float* __restrict__ W_hh,
    const float* __restrict__ xp,              // [STEPS][GROWS]
    unsigned long long* __restrict__ hbuf,     // [2][HIDDEN]
    float* __restrict__ hs32,                  // [STEPS][HIDDEN]
    __bf16* __restrict__ hsbf,                 // [STEPS][HIDDEN]
    const float* __restrict__ W_out,           // converter input
    unsigned short* __restrict__ Wb,           // converter output (bf16 bits)
    const int wbf)
{
    const int tid = threadIdx.x;

    if (blockIdx.x >= 32) {
        // ---- embedded converter (runs on CUs the scan leaves idle) ----
        const int cb = blockIdx.x - 32;              // 0..223
        const int stride = 224 * 256 * 4;
        for (int i = (cb * 256 + tid) * 4; i < WB_HEAD_ELEMS; i += stride) {
            const float4 v = *(const float4*)(W_out + i);
            ushort4 o;
            o.x = f2bf_u16(v.x); o.y = f2bf_u16(v.y);
            o.z = f2bf_u16(v.z); o.w = f2bf_u16(v.w);
            *(ushort4*)(Wb + i) = o;
        }
        return;
    }

    const int rg  = tid >> 6;
    const int kc  = tid & 63;
    const int w   = blockIdx.x * 4 + rg;   // global wave 0..127
    const int j0  = w * 4;

    __shared__ float hlds[2][HIDDEN];      // double-buffered h broadcast

    // lane -> (gate, elem) ownership after fold
    const int t_own  = ((kc & 1) << 1) | ((kc >> 1) & 1);
    const int jj_own = (((kc >> 2) & 1) << 1) | ((kc >> 3) & 1);
    const int row_own = t_own * HIDDEN + j0 + jj_own;

    // ---- W_hh slice into registers: 16 rows x 8 k-chunk per lane ----
    float Whh[4][4][8];
#pragma unroll
    for (int t = 0; t < 4; ++t) {
#pragma unroll
        for (int jj = 0; jj < 4; ++jj) {
            const int row = t * HIDDEN + j0 + jj;
            const float4* ph = (const float4*)(W_hh + (size_t)row * HIDDEN + kc * 8);
            const float4 h0 = ph[0], h1 = ph[1];
            Whh[t][jj][0] = h0.x; Whh[t][jj][1] = h0.y; Whh[t][jj][2] = h0.z; Whh[t][jj][3] = h0.w;
            Whh[t][jj][4] = h1.x; Whh[t][jj][5] = h1.y; Whh[t][jj][6] = h1.z; Whh[t][jj][7] = h1.w;
        }
    }

    float c_state = 0.0f;
    float xpv_next = xp[row_own];          // xp for s = 0
    const int qi = rg * 128 + kc * 2;      // my quarter words

    for (int s = 0; s < STEPS; ++s) {
        const int p = s & 1;
        const unsigned expect = (unsigned)s;
        const float xpv = xpv_next;

        // prefetch next step's xp (independent of h; hides MALL latency)
        const int sn = (s + 1 < STEPS) ? (s + 1) : (STEPS - 1);
        xpv_next = xp[(size_t)sn * GROWS + row_own];

        // ---- poll my quarter of version s directly (tagged data words) ----
        const unsigned long long* hb = hbuf + (size_t)p * HIDDEN + qi;
        unsigned long long va, vb;
        for (;;) {
            va = __hip_atomic_load(hb,     __ATOMIC_RELAXED, __HIP_MEMORY_SCOPE_AGENT);
            vb = __hip_atomic_load(hb + 1, __ATOMIC_RELAXED, __HIP_MEMORY_SCOPE_AGENT);
            const bool ok = ((unsigned)(va >> 32) == expect) &
                            ((unsigned)(vb >> 32) == expect);
            if (__all((int)ok)) break;
            __builtin_amdgcn_s_sleep(1);
        }
        hlds[p][qi]     = __uint_as_float((unsigned)(va & 0xffffffffULL));
        hlds[p][qi + 1] = __uint_as_float((unsigned)(vb & 0xffffffffULL));
        __syncthreads();

        // ---- h from LDS ----
        float hreg[8];
        {
            const float4 a = *(const float4*)&hlds[p][kc * 8];
            const float4 b = *(const float4*)&hlds[p][kc * 8 + 4];
            hreg[0] = a.x; hreg[1] = a.y; hreg[2] = a.z; hreg[3] = a.w;
            hreg[4] = b.x; hreg[5] = b.y; hreg[6] = b.z; hreg[7] = b.w;
        }

        // ---- h contribution: 16 rows x 8 k ----
        float acc[16];
#pragma unroll
        for (int t = 0; t < 4; ++t) {
#pragma unroll
            for (int jj = 0; jj < 4; ++jj) {
                float a = Whh[t][jj][0] * hreg[0];
#pragma unroll
                for (int kk = 1; kk < 8; ++kk)
                    a = fmaf(Whh[t][jj][kk], hreg[kk], a);
                acc[t * 4 + jj] = a;
            }
        }

        // ---- fold-reduce 16 x 64 lanes -> full sum per lane ----
#pragma unroll
        for (int i = 0; i < 8; ++i) {
            const float send = (kc & 1) ? acc[i] : acc[i + 8];
            const float keep = (kc & 1) ? acc[i + 8] : acc[i];
            acc[i] = keep + __shfl_xor(send, 1, 64);
        }
#pragma unroll
        for (int i = 0; i < 4; ++i) {
            const float send = (kc & 2) ? acc[i] : acc[i + 4];
            const float keep = (kc & 2) ? acc[i + 4] : acc[i];
            acc[i] = keep + __shfl_xor(send, 2, 64);
        }
#pragma unroll
        for (int i = 0; i < 2; ++i) {
            const float send = (kc & 4) ? acc[i] : acc[i + 2];
            const float keep = (kc & 4) ? acc[i + 2] : acc[i];
            acc[i] = keep + __shfl_xor(send, 4, 64);
        }
        {
            const float send = (kc & 8) ? acc[0] : acc[1];
            const float keep = (kc & 8) ? acc[1] : acc[0];
            acc[0] = keep + __shfl_xor(send, 8, 64);
        }
        float a = acc[0];
        a += __shfl_xor(a, 16, 64);
        a += __shfl_xor(a, 32, 64);
        a += xpv;   // full gate pre-activation for (t_own, jj_own)

        // ---- gather the 4 gates of MY element ----
        const float g00 = a;
        const float g01 = __shfl_xor(a, 1, 64);
        const float g10 = __shfl_xor(a, 2, 64);
        const float g11 = __shfl_xor(g01, 2, 64);
        float gi = sel4(g00, g10, g01, g11, t_own);
        float gf = sel4(g00, g10, g01, g11, t_own ^ 1);
        float gg = sel4(g00, g10, g01, g11, t_own ^ 2);
        float go = sel4(g00, g10, g01, g11, t_own ^ 3);

        gi = sigmoid_f(gi);
        gf = sigmoid_f(gf);
        gg = tanh_f(gg);
        go = sigmoid_f(go);
        c_state = gf * c_state + gi * gg;
        const float hnew = go * tanh_f(c_state);

        // ---- publish version s+1 FIRST (critical), then trace stores ----
        if ((kc & 0x33) == 0) {
            const int j = j0 + jj_own;
            const unsigned long long pack =
                ((unsigned long long)(unsigned)(s + 1) << 32) |
                (unsigned long long)__float_as_uint(hnew);
            __hip_atomic_store(hbuf + (size_t)((s + 1) & 1) * HIDDEN + j, pack,
                               __ATOMIC_RELAXED, __HIP_MEMORY_SCOPE_AGENT);
            hs32[(size_t)s * HIDDEN + j] = hnew;
            if (wbf) hsbf[(size_t)s * HIDDEN + j] = (__bf16)hnew;
        }
    }
}

// ---------------------------------------------------------------------------
// Kernel 1b: convert the xp-protected tail of W_out after the scan.
// ---------------------------------------------------------------------------
__global__ __launch_bounds__(256) void convert_tail_kernel(
    const float* __restrict__ W, unsigned short* __restrict__ Wb,
    int lo, int n)
{
    const int stride = gridDim.x * blockDim.x * 4;
    for (int i = lo + (blockIdx.x * blockDim.x + threadIdx.x) * 4; i < n; i += stride) {
        const float4 v = *(const float4*)(W + i);
        ushort4 o;
        o.x = f2bf_u16(v.x); o.y = f2bf_u16(v.y);
        o.z = f2bf_u16(v.z); o.w = f2bf_u16(v.w);
        *(ushort4*)(Wb + i) = o;
    }
}

// ---------------------------------------------------------------------------
// Kernel 2b: logits = hs_bf16 @ Wb^T + b_out via MFMA (M=1024,N=32000,K=512).
// ---------------------------------------------------------------------------
__global__ __launch_bounds__(256) void logits_mfma_kernel(
    const __bf16* __restrict__ A,
    const __bf16* __restrict__ B,
    const float* __restrict__ b_out,
    float* __restrict__ out)
{
    __shared__ char AsR[16384];
    __shared__ char BsR[16384];
    const int tid  = threadIdx.x;
    const int lane = tid & 63;
    const int wave = tid >> 6;
    const int wm = (wave >> 1) * 64;
    const int wn = (wave & 1) * 64;
    const int n0 = blockIdx.x * 128;
    const int m0 = blockIdx.y * 128;

    f32x4 acc[4][4] = {};

    for (int k0 = 0; k0 < HIDDEN; k0 += 64) {
        if (k0) __syncthreads();
#pragma unroll
        for (int i = 0; i < 4; ++i) {
            const int o   = (tid + i * 256) << 4;
            const int row = o >> 7;
            const int cb  = o & 127;
            const int sc  = cb ^ ((row & 7) << 4);
            const bf16x8 av = *(const bf16x8*)(A + (size_t)(m0 + row) * HIDDEN + k0 + (cb >> 1));
            const bf16x8 bv = *(const bf16x8*)(B + (size_t)(n0 + row) * HIDDEN + k0 + (cb >> 1));
            *(bf16x8*)(AsR + row * 128 + sc) = av;
            *(bf16x8*)(BsR + row * 128 + sc) = bv;
        }
        __syncthreads();
#pragma unroll
        for (int ks = 0; ks < 2; ++ks) {
            const int kb = ks * 64 + ((lane >> 4) << 4);
            bf16x8 af[4], bfr[4];
#pragma unroll
            for (int mi = 0; mi < 4; ++mi) {
                const int r = wm + mi * 16 + (lane & 15);
                af[mi] = *(const bf16x8*)(AsR + r * 128 + (kb ^ ((r & 7) << 4)));
            }
#pragma unroll
            for (int ni = 0; ni < 4; ++ni) {
                const int r = wn + ni * 16 + (lane & 15);
                bfr[ni] = *(const bf16x8*)(BsR + r * 128 + (kb ^ ((r & 7) << 4)));
            }
#pragma unroll
            for (int mi = 0; mi < 4; ++mi)
#pragma unroll
                for (int ni = 0; ni < 4; ++ni)
                    acc[mi][ni] = __builtin_amdgcn_mfma_f32_16x16x32_bf16(
                        af[mi], bfr[ni], acc[mi][ni], 0, 0, 0);
        }
    }

#pragma unroll
    for (int ni = 0; ni < 4; ++ni) {
        const int col = n0 + wn + ni * 16 + (lane & 15);
        const float bo = b_out[col];
#pragma unroll
        for (int mi = 0; mi < 4; ++mi) {
            const int r0 = m0 + wm + mi * 16 + ((lane >> 4) << 2);
#pragma unroll
            for (int qq = 0; qq < 4; ++qq)
                out[(size_t)(r0 + qq) * VOCAB + col] = acc[mi][ni][qq] + bo;
        }
    }
}

// ---------------------------------------------------------------------------
// Kernel 2-fallback: fp32 vector GEMM.
// ---------------------------------------------------------------------------
__global__ __launch_bounds__(256) void logits_kernel(
    const float* __restrict__ hs,
    const float* __restrict__ W_out,
    const float* __restrict__ b_out,
    float* __restrict__ out)
{
    __shared__ float As[64][65];
    __shared__ float Bs[64][65];
    const int tid = threadIdx.x;
    const int tx = tid & 15, ty = tid >> 4;
    const int v0 = blockIdx.x * 64;
    const int s0 = blockIdx.y * 64;
    float accv[4][4] = {};

    for (int k0 = 0; k0 < HIDDEN; k0 += 64) {
#pragma unroll
        for (int i = 0; i < 4; ++i) {
            const int idx = tid + i * 256;
            const int r = idx >> 4, q = idx & 15;
            const float4 a = *(const float4*)(hs + (size_t)(s0 + r) * HIDDEN + k0 + q * 4);
            As[r][q * 4 + 0] = a.x; As[r][q * 4 + 1] = a.y;
            As[r][q * 4 + 2] = a.z; As[r][q * 4 + 3] = a.w;
            const float4 b = *(const float4*)(W_out + (size_t)(v0 + r) * HIDDEN + k0 + q * 4);
            Bs[r][q * 4 + 0] = b.x; Bs[r][q * 4 + 1] = b.y;
            Bs[r][q * 4 + 2] = b.z; Bs[r][q * 4 + 3] = b.w;
        }
        __syncthreads();
#pragma unroll 16
        for (int kk = 0; kk < 64; ++kk) {
            float av[4], bv[4];
#pragma unroll
            for (int i = 0; i < 4; ++i) av[i] = As[ty * 4 + i][kk];
#pragma unroll
            for (int j = 0; j < 4; ++j) bv[j] = Bs[tx * 4 + j][kk];
#pragma unroll
            for (int i = 0; i < 4; ++i)
#pragma unroll
                for (int j = 0; j < 4; ++j)
                    accv[i][j] = fmaf(av[i], bv[j], accv[i][j]);
        }
        __syncthreads();
    }
#pragma unroll
    for (int i = 0; i < 4; ++i) {
        const int s = s0 + ty * 4 + i;
#pragma unroll
        for (int j = 0; j < 4; ++j) {
            const int v = v0 + tx * 4 + j;
            out[(size_t)s * VOCAB + v] = accv[i][j] + b_out[v];
        }
    }
}

// ---------------------------------------------------------------------------
// Kernel 3: in-place row softmax, one WG per row of 32000.
// ---------------------------------------------------------------------------
__global__ __launch_bounds__(256) void softmax_kernel(float* __restrict__ out)
{
    const int row = blockIdx.x;
    float* p = out + (size_t)row * VOCAB;
    const int tid = threadIdx.x;
    __shared__ float redm[4];
    __shared__ float reds[4];

    float m = -3.402823466e38f;
    for (int idx = tid * 4; idx < VOCAB; idx += 1024) {
        const float4 v = *(const float4*)(p + idx);
        m = fmaxf(m, fmaxf(fmaxf(v.x, v.y), fmaxf(v.z, v.w)));
    }
#pragma unroll
    for (int d = 1; d < 64; d <<= 1) m = fmaxf(m, __shfl_xor(m, d, 64));
    if ((tid & 63) == 0) redm[tid >> 6] = m;
    __syncthreads();
    m = fmaxf(fmaxf(redm[0], redm[1]), fmaxf(redm[2], redm[3]));

    float sum = 0.f;
    for (int idx = tid * 4; idx < VOCAB; idx += 1024) {
        const float4 v = *(const float4*)(p + idx);
        sum += __expf(v.x - m) + __expf(v.y - m) + __expf(v.z - m) + __expf(v.w - m);
    }
#pragma unroll
    for (int d = 1; d < 64; d <<= 1) sum += __shfl_xor(sum, d, 64);
    if ((tid & 63) == 0) reds[tid >> 6] = sum;
    __syncthreads();
    sum = reds[0] + reds[1] + reds[2] + reds[3];
    const float inv = 1.0f / sum;

    for (int idx = tid * 4; idx < VOCAB; idx += 1024) {
        const float4 v = *(const float4*)(p + idx);
        float4 o;
        o.x = __expf(v.x - m) * inv;
        o.y = __expf(v.y - m) * inv;
        o.z = __expf(v.z - m) * inv;
        o.w = __expf(v.w - m) * inv;
        *(float4*)(p + idx) = o;
    }
}

// ---------------------------------------------------------------------------
// launch
// ---------------------------------------------------------------------------
extern "C" void kernel_launch(void* const* d_in, const int* in_sizes, int n_in,
                              void* d_out, int out_size, void* d_ws, size_t ws_size,
                              hipStream_t stream)
{
    const float* features = (const float*)d_in[0];
    const int*   captions = (const int*)d_in[1];
    const float* emb      = (const float*)d_in[2];
    const float* W_ih     = (const float*)d_in[3];
    const float* W_hh     = (const float*)d_in[4];
    const float* b_ih     = (const float*)d_in[5];
    const float* b_hh     = (const float*)d_in[6];
    const float* W_out    = (const float*)d_in[7];
    const float* b_out    = (const float*)d_in[8];
    float* out = (float*)d_out;

    char* ws = (char*)d_ws;
    unsigned long long* hbuf = (unsigned long long*)(ws + WS_HBUF);
    float*              hs32 = (float*)(ws + WS_HS32);
    __bf16*             hsbf = (__bf16*)(ws + WS_HSBF);
    __bf16*             Wb   = (__bf16*)(ws + WS_WB);
    const bool mfma_ok = ws_size >= WS_NEED;
    // xp: tail 8 MB of the Wb region (mfma path; converter skips that range
    // until after the scan), or Wb region start in fallback (Wb unused).
    float* xpb = mfma_ok ? (float*)(ws + WS_WB + WS_XPOFF) : (float*)(ws + WS_WB);

    // reset tagged h words (graph-replay determinism)
    hipMemsetAsync(d_ws, 0, 8192, stream);

    xproj_kernel<<<dim3(GROWS / 64, STEPS / 64), 256, 0, stream>>>(
        features, captions, emb, W_ih, b_ih, b_hh, xpb);

    lstm_scan_kernel<<<mfma_ok ? 256 : 32, 256, 0, stream>>>(
        W_hh, xpb, hbuf, hs32, hsbf,
        W_out, (unsigned short*)Wb, mfma_ok ? 1 : 0);

    if (mfma_ok) {
        convert_tail_kernel<<<512, 256, 0, stream>>>(
            W_out, (unsigned short*)Wb, WB_HEAD_ELEMS, VOCAB * HIDDEN);
        logits_mfma_kernel<<<dim3(VOCAB / 128, STEPS / 128), 256, 0, stream>>>(
            hsbf, Wb, b_out, out);
    } else {
        logits_kernel<<<dim3(VOCAB / 64, STEPS / 64), 256, 0, stream>>>(
            hs32, W_out, b_out, out);
    }
    softmax_kernel<<<STEPS, 256, 0, stream>>>(out);
}